// Round 1
// baseline (13197.806 us; speedup 1.0000x reference)
//
#include <hip/hip_runtime.h>
#include <hip/hip_bf16.h>
#include <math.h>

typedef __hip_bfloat16 bf16;
typedef __attribute__((ext_vector_type(8))) __bf16 bf16x8;
typedef __attribute__((ext_vector_type(4))) float f32x4;

#define HDIM 768
#define MROWS 6144
#define NCHUNK 6

__device__ __forceinline__ float bf2f(unsigned int u) {
  union { unsigned int i; float f; } c; c.i = u << 16; return c.f;
}

__device__ __forceinline__ void gload16(const void* g, void* l) {
  __builtin_amdgcn_global_load_lds((const __attribute__((address_space(1))) void*)g,
                                   (__attribute__((address_space(3))) void*)l, 16, 0, 0);
}

// ---------------- weight transpose + f32->bf16 convert ----------------
// Converts one layer's 6 matrices into wt as transposed bf16: Wt[N][K] = W[K][N].
// Layout in wt (elements): Wqt@0, Wkt@589824, Wvt@1179648, Wot@1769472,
//                          Wit@2359296 (3072x768), Wo2t@4718592 (768x3072)
__global__ __launch_bounds__(256) void wconv(
    const float* __restrict__ Wq, const float* __restrict__ Wk,
    const float* __restrict__ Wv, const float* __restrict__ Wo,
    const float* __restrict__ Wi, const float* __restrict__ Wo2,
    bf16* __restrict__ wt)
{
  __shared__ float tile[32][33];
  const int bid = blockIdx.x;
  const float* src; bf16* dst; int K, N, tIdx;
  if (bid < 2304) {
    int m = bid / 576; tIdx = bid % 576; K = 768; N = 768;
    src = (m == 0) ? Wq : (m == 1) ? Wk : (m == 2) ? Wv : Wo;
    dst = wt + (size_t)m * 589824;
  } else if (bid < 4608) {
    tIdx = bid - 2304; K = 768; N = 3072; src = Wi; dst = wt + 2359296;
  } else {
    tIdx = bid - 4608; K = 3072; N = 768; src = Wo2; dst = wt + 4718592;
  }
  const int tilesN = N >> 5;
  const int tn = tIdx % tilesN, tk = tIdx / tilesN;
  const int n0 = tn * 32, k0 = tk * 32;
  const int tx = threadIdx.x & 31, ty = threadIdx.x >> 5;
#pragma unroll
  for (int r = 0; r < 4; ++r)
    tile[ty + r * 8][tx] = src[(size_t)(k0 + ty + r * 8) * N + n0 + tx];
  __syncthreads();
#pragma unroll
  for (int r = 0; r < 4; ++r)
    dst[(size_t)(n0 + ty + r * 8) * K + k0 + tx] = __float2bfloat16(tile[tx][ty + r * 8]);
}

// ---------------- GEMM: C = A[M,K](bf16) @ Bt[N,K]^T(bf16) + bias, epilogues ----------------
// epi 0: fused QKV -> bf16 out at qkv + (n/768)*M*768, bias selected from b0/b1/b2
// epi 2: gelu(acc+bias) -> bf16 out [M,N]
// epi 3: acc+bias -> f32 out [M,N]
__global__ __launch_bounds__(256) void gemm_bf16(
    const bf16* __restrict__ A, const bf16* __restrict__ Bt,
    void* __restrict__ out, const float* __restrict__ b0,
    const float* __restrict__ b1, const float* __restrict__ b2,
    int M, int N, int K, int epi)
{
  __shared__ __align__(16) bf16 As[128 * 32];
  __shared__ __align__(16) bf16 Bs[128 * 32];
  const int m0 = blockIdx.y * 128;
  const int n0 = blockIdx.x * 128;
  const int t = threadIdx.x;
  const int lane = t & 63;
  const int w = t >> 6;
  const int wr = w >> 1, wc = w & 1;

  f32x4 acc[4][4];
#pragma unroll
  for (int i = 0; i < 4; ++i)
#pragma unroll
    for (int j = 0; j < 4; ++j) acc[i][j] = (f32x4)0.f;

  const int idx = t * 8;            // element offset within 128x32 tile
  const int rowA = idx >> 5;        // 0..63
  const int colA = idx & 31;        // 0,8,16,24
  const bf16* gA = A + (size_t)(m0 + rowA) * K + colA;
  const bf16* gB = Bt + (size_t)(n0 + rowA) * K + colA;
  const int kofs = (lane >> 4) * 8;
  const int fr = lane & 15;

  for (int k0 = 0; k0 < K; k0 += 32) {
    gload16(gA + k0, As + idx);
    gload16(gA + k0 + (size_t)64 * K, As + idx + 2048);
    gload16(gB + k0, Bs + idx);
    gload16(gB + k0 + (size_t)64 * K, Bs + idx + 2048);
    __syncthreads();
    bf16x8 af[4], bfr[4];
#pragma unroll
    for (int m = 0; m < 4; ++m)
      af[m] = *(const bf16x8*)(As + (wr * 64 + m * 16 + fr) * 32 + kofs);
#pragma unroll
    for (int n = 0; n < 4; ++n)
      bfr[n] = *(const bf16x8*)(Bs + (wc * 64 + n * 16 + fr) * 32 + kofs);
#pragma unroll
    for (int m = 0; m < 4; ++m)
#pragma unroll
      for (int n = 0; n < 4; ++n)
        acc[m][n] = __builtin_amdgcn_mfma_f32_16x16x32_bf16(af[m], bfr[n], acc[m][n], 0, 0, 0);
    __syncthreads();
  }

  const int rr = (lane >> 4) * 4;
  const int cc0 = lane & 15;
  if (epi == 0) {
    const int mat = n0 / HDIM;   // uniform per block (128 | 768)
    const float* bias = (mat == 0) ? b0 : (mat == 1) ? b1 : b2;
    bf16* dst = (bf16*)out + (size_t)mat * MROWS * HDIM;
    const int nl = n0 - mat * HDIM;
#pragma unroll
    for (int m = 0; m < 4; ++m)
#pragma unroll
      for (int n = 0; n < 4; ++n) {
        const int row = m0 + wr * 64 + m * 16 + rr;
        const int col = nl + wc * 64 + n * 16 + cc0;
        const float bv = bias[col];
#pragma unroll
        for (int r = 0; r < 4; ++r)
          dst[(size_t)(row + r) * HDIM + col] = __float2bfloat16(acc[m][n][r] + bv);
      }
  } else if (epi == 2) {
    bf16* dst = (bf16*)out;
#pragma unroll
    for (int m = 0; m < 4; ++m)
#pragma unroll
      for (int n = 0; n < 4; ++n) {
        const int row = m0 + wr * 64 + m * 16 + rr;
        const int col = n0 + wc * 64 + n * 16 + cc0;
        const float bv = b0[col];
#pragma unroll
        for (int r = 0; r < 4; ++r) {
          float v = acc[m][n][r] + bv;
          v = 0.5f * v * (1.0f + erff(v * 0.70710678118654752f));
          dst[(size_t)(row + r) * N + col] = __float2bfloat16(v);
        }
      }
  } else {
    float* dst = (float*)out;
#pragma unroll
    for (int m = 0; m < 4; ++m)
#pragma unroll
      for (int n = 0; n < 4; ++n) {
        const int row = m0 + wr * 64 + m * 16 + rr;
        const int col = n0 + wc * 64 + n * 16 + cc0;
        const float bv = b0[col];
#pragma unroll
        for (int r = 0; r < 4; ++r)
          dst[(size_t)(row + r) * N + col] = acc[m][n][r] + bv;
      }
  }
}

// ---------------- sliding-window attention ----------------
// grid (chunk=6, head=12, batch=8), 128 threads = 1 query each.
__global__ __launch_bounds__(128) void attn_kernel(
    const bf16* __restrict__ qkv, bf16* __restrict__ attb)
{
  const int c = blockIdx.x, h = blockIdx.y, b = blockIdx.z;
  __shared__ __align__(16) bf16 Ks[128 * 64];
  __shared__ __align__(16) bf16 Vs[128 * 64];
  const int tid = threadIdx.x;
  const bf16* Km = qkv + (size_t)4718592;
  const bf16* Vm = qkv + (size_t)9437184;
  const int qrow = b * 768 + c * 128 + tid;

  float q[64], acc[64];
  {
    const uint4* qp = (const uint4*)(qkv + (size_t)qrow * HDIM + h * 64);
#pragma unroll
    for (int i = 0; i < 8; ++i) {
      uint4 u = qp[i];
      q[i*8+0] = bf2f(u.x & 0xffffu) * 0.125f; q[i*8+1] = bf2f(u.x >> 16) * 0.125f;
      q[i*8+2] = bf2f(u.y & 0xffffu) * 0.125f; q[i*8+3] = bf2f(u.y >> 16) * 0.125f;
      q[i*8+4] = bf2f(u.z & 0xffffu) * 0.125f; q[i*8+5] = bf2f(u.z >> 16) * 0.125f;
      q[i*8+6] = bf2f(u.w & 0xffffu) * 0.125f; q[i*8+7] = bf2f(u.w >> 16) * 0.125f;
    }
  }
#pragma unroll
  for (int d = 0; d < 64; ++d) acc[d] = 0.f;
  float mrun = -1e30f, lrun = 0.f;

  for (int cc = c - 1; cc <= c + 1; ++cc) {
    if (cc < 0 || cc >= NCHUNK) continue;   // uniform branch (blockIdx-based)
    __syncthreads();
    {
      const uint4* ks = (const uint4*)(Km + (size_t)(b * 768 + cc * 128 + tid) * HDIM + h * 64);
      const uint4* vs = (const uint4*)(Vm + (size_t)(b * 768 + cc * 128 + tid) * HDIM + h * 64);
      uint4* kd = (uint4*)Ks + tid * 8;
      uint4* vd = (uint4*)Vs + tid * 8;
#pragma unroll
      for (int i = 0; i < 8; ++i) { kd[i] = ks[i]; vd[i] = vs[i]; }
    }
    __syncthreads();
    const int mode = (cc < c) ? 0 : ((cc == c) ? 1 : 2);
#pragma unroll 1
    for (int jb = 0; jb < 8; ++jb) {
      float sv[16];
      float bm = -1e30f;
#pragma unroll
      for (int jj = 0; jj < 16; ++jj) {
        const int j = jb * 16 + jj;
        const uint4* kr = (const uint4*)(Ks + j * 64);
        float s = 0.f;
#pragma unroll
        for (int i = 0; i < 8; ++i) {
          uint4 u = kr[i];
          s += q[i*8+0] * bf2f(u.x & 0xffffu); s += q[i*8+1] * bf2f(u.x >> 16);
          s += q[i*8+2] * bf2f(u.y & 0xffffu); s += q[i*8+3] * bf2f(u.y >> 16);
          s += q[i*8+4] * bf2f(u.z & 0xffffu); s += q[i*8+5] * bf2f(u.z >> 16);
          s += q[i*8+6] * bf2f(u.w & 0xffffu); s += q[i*8+7] * bf2f(u.w >> 16);
        }
        const bool valid = (mode == 1) || (mode == 0 ? (j >= tid) : (j <= tid));
        sv[jj] = valid ? s : -1e30f;
        bm = fmaxf(bm, sv[jj]);
      }
      const float mnew = fmaxf(fmaxf(mrun, bm), -1e20f);
      const float scale = __expf(mrun - mnew);
      lrun *= scale;
#pragma unroll
      for (int d = 0; d < 64; ++d) acc[d] *= scale;
      mrun = mnew;
#pragma unroll
      for (int jj = 0; jj < 16; ++jj) {
        const int j = jb * 16 + jj;
        const float p = __expf(sv[jj] - mrun);   // exactly 0 for masked (-1e30)
        lrun += p;
        const uint4* vr = (const uint4*)(Vs + j * 64);
#pragma unroll
        for (int i = 0; i < 8; ++i) {
          uint4 u = vr[i];
          acc[i*8+0] += p * bf2f(u.x & 0xffffu); acc[i*8+1] += p * bf2f(u.x >> 16);
          acc[i*8+2] += p * bf2f(u.y & 0xffffu); acc[i*8+3] += p * bf2f(u.y >> 16);
          acc[i*8+4] += p * bf2f(u.z & 0xffffu); acc[i*8+5] += p * bf2f(u.z >> 16);
          acc[i*8+6] += p * bf2f(u.w & 0xffffu); acc[i*8+7] += p * bf2f(u.w >> 16);
        }
      }
    }
  }
  const float rl = 1.f / lrun;
  bf16* orow = attb + (size_t)qrow * HDIM + h * 64;
#pragma unroll
  for (int d = 0; d < 64; ++d) orow[d] = __float2bfloat16(acc[d] * rl);
}

// ---------------- LayerNorm kernels ----------------
__device__ __forceinline__ void blk_reduce2(float& s1, float& s2) {
#pragma unroll
  for (int o = 32; o > 0; o >>= 1) { s1 += __shfl_xor(s1, o); s2 += __shfl_xor(s2, o); }
  __shared__ float red[8];
  const int w = threadIdx.x >> 6;
  if ((threadIdx.x & 63) == 0) { red[w] = s1; red[4 + w] = s2; }
  __syncthreads();
  s1 = red[0] + red[1] + red[2] + red[3];
  s2 = red[4] + red[5] + red[6] + red[7];
}

__global__ __launch_bounds__(256) void embed_ln(
    const float* __restrict__ emb, const float* __restrict__ pos,
    const float* __restrict__ tte, const float* __restrict__ g,
    const float* __restrict__ bt, float* __restrict__ x, bf16* __restrict__ xb)
{
  const int row = blockIdx.x;
  const int s = row % 768;
  const int t = threadIdx.x;
  const size_t base = (size_t)row * HDIM;
  const size_t pbase = (size_t)(s + 2) * HDIM;
  float v[3];
#pragma unroll
  for (int i = 0; i < 3; ++i) {
    const int idx = t + i * 256;
    v[i] = emb[base + idx] + pos[pbase + idx] + tte[idx];
  }
  float s1 = v[0] + v[1] + v[2];
  float s2 = v[0]*v[0] + v[1]*v[1] + v[2]*v[2];
  blk_reduce2(s1, s2);
  const float mu = s1 * (1.f / 768.f);
  const float var = s2 * (1.f / 768.f) - mu * mu;
  const float inv = rsqrtf(var + 1e-12f);
#pragma unroll
  for (int i = 0; i < 3; ++i) {
    const int idx = t + i * 256;
    const float o = (v[i] - mu) * inv * g[idx] + bt[idx];
    x[base + idx] = o;
    xb[base + idx] = __float2bfloat16(o);
  }
}

__global__ __launch_bounds__(256) void add_ln(
    const float* __restrict__ tmp, float* __restrict__ x, bf16* __restrict__ xb,
    const float* __restrict__ g, const float* __restrict__ bt)
{
  const int row = blockIdx.x;
  const int t = threadIdx.x;
  const size_t base = (size_t)row * HDIM;
  float v[3];
#pragma unroll
  for (int i = 0; i < 3; ++i) {
    const int idx = t + i * 256;
    v[i] = x[base + idx] + tmp[base + idx];
  }
  float s1 = v[0] + v[1] + v[2];
  float s2 = v[0]*v[0] + v[1]*v[1] + v[2]*v[2];
  blk_reduce2(s1, s2);
  const float mu = s1 * (1.f / 768.f);
  const float var = s2 * (1.f / 768.f) - mu * mu;
  const float inv = rsqrtf(var + 1e-12f);
#pragma unroll
  for (int i = 0; i < 3; ++i) {
    const int idx = t + i * 256;
    const float o = (v[i] - mu) * inv * g[idx] + bt[idx];
    x[base + idx] = o;
    xb[base + idx] = __float2bfloat16(o);
  }
}

// ---------------- gate ----------------
__global__ __launch_bounds__(256) void gate_kernel(
    const float* __restrict__ x, const float* __restrict__ gw,
    const float* __restrict__ gb, float* __restrict__ out)
{
  const int row = blockIdx.x * 4 + (threadIdx.x >> 6);
  const int lane = threadIdx.x & 63;
  const float* xr = x + (size_t)row * HDIM;
  float s = 0.f;
#pragma unroll
  for (int i = 0; i < 12; ++i) s += xr[lane + i * 64] * gw[lane + i * 64];
#pragma unroll
  for (int o = 32; o > 0; o >>= 1) s += __shfl_xor(s, o);
  if (lane == 0) out[row] = s + gb[0];
}

// ---------------- host ----------------
extern "C" void kernel_launch(void* const* d_in, const int* in_sizes, int n_in,
                              void* d_out, int out_size, void* d_ws, size_t ws_size,
                              hipStream_t stream)
{
  const float* emb = (const float*)d_in[0];
  const float* pos = (const float*)d_in[2];
  const float* tte = (const float*)d_in[3];
  const float* eg  = (const float*)d_in[4];
  const float* eb  = (const float*)d_in[5];
  const float* Wq  = (const float*)d_in[6];
  const float* bq  = (const float*)d_in[7];
  const float* Wk  = (const float*)d_in[8];
  const float* bk  = (const float*)d_in[9];
  const float* Wv  = (const float*)d_in[10];
  const float* bv  = (const float*)d_in[11];
  const float* Wo  = (const float*)d_in[12];
  const float* bo  = (const float*)d_in[13];
  const float* g1  = (const float*)d_in[14];
  const float* be1 = (const float*)d_in[15];
  const float* Wi  = (const float*)d_in[16];
  const float* bi  = (const float*)d_in[17];
  const float* Wo2 = (const float*)d_in[18];
  const float* bo2 = (const float*)d_in[19];
  const float* g2  = (const float*)d_in[20];
  const float* be2 = (const float*)d_in[21];
  const float* gw  = (const float*)d_in[22];
  const float* gb  = (const float*)d_in[23];

  // workspace layout (bytes):
  //   wt   @ 0        : 7,077,888 bf16 transposed weights (per layer, reused)
  //   xb   @ 14155776 : 4,718,592 bf16 residual-stream copy
  //   qkvb @ 23592960 : 4 x 4,718,592 bf16 (q,k,v,attn-out; FFN1 output aliases all 4)
  //   tmp  @ 61341696 : 4,718,592 f32 pre-LN GEMM output
  char* wsp = (char*)d_ws;
  bf16* wt   = (bf16*)wsp;
  bf16* xb   = (bf16*)(wsp + 14155776);
  bf16* qkvb = (bf16*)(wsp + 23592960);
  float* tmp = (float*)(wsp + 61341696);
  bf16* attb = qkvb + (size_t)3 * 4718592;
  bf16* ffb  = qkvb;                 // alias: q/k/v/att dead when FFN1 runs
  float* x   = (float*)d_out;        // f32 residual stream lives in d_out
  float* gate = x + 4718592;

  embed_ln<<<6144, 256, 0, stream>>>(emb, pos, tte, eg, eb, x, xb);

  for (int l = 0; l < 12; ++l) {
    wconv<<<6912, 256, 0, stream>>>(Wq + (size_t)l * 589824, Wk + (size_t)l * 589824,
                                    Wv + (size_t)l * 589824, Wo + (size_t)l * 589824,
                                    Wi + (size_t)l * 2359296, Wo2 + (size_t)l * 2359296, wt);
    gemm_bf16<<<dim3(18, 48), 256, 0, stream>>>(xb, wt, qkvb,
        bq + l * 768, bk + l * 768, bv + l * 768, 6144, 2304, 768, 0);
    attn_kernel<<<dim3(6, 12, 8), 128, 0, stream>>>(qkvb, attb);
    gemm_bf16<<<dim3(6, 48), 256, 0, stream>>>(attb, wt + 1769472, tmp,
        bo + l * 768, nullptr, nullptr, 6144, 768, 768, 3);
    add_ln<<<6144, 256, 0, stream>>>(tmp, x, xb, g1 + l * 768, be1 + l * 768);
    gemm_bf16<<<dim3(24, 48), 256, 0, stream>>>(xb, wt + 2359296, ffb,
        bi + l * 3072, nullptr, nullptr, 6144, 3072, 768, 2);
    gemm_bf16<<<dim3(6, 48), 256, 0, stream>>>(ffb, wt + 4718592, tmp,
        bo2 + l * 768, nullptr, nullptr, 6144, 768, 3072, 3);
    add_ln<<<6144, 256, 0, stream>>>(tmp, x, xb, g2 + l * 768, be2 + l * 768);
  }

  gate_kernel<<<1536, 256, 0, stream>>>(x, gw, gb, gate);
}

// Round 2
// 3797.729 us; speedup vs baseline: 3.4752x; 3.4752x over previous
//
#include <hip/hip_runtime.h>
#include <hip/hip_bf16.h>
#include <math.h>

typedef __hip_bfloat16 bf16;
typedef __attribute__((ext_vector_type(8))) __bf16 bf16x8;
typedef __attribute__((ext_vector_type(4))) float f32x4;

#define HDIM 768
#define MROWS 6144
#define NCHUNK 6

__device__ __forceinline__ float bf2f(unsigned int u) {
  union { unsigned int i; float f; } c; c.i = u << 16; return c.f;
}

__device__ __forceinline__ void gload16(const void* g, void* l) {
  __builtin_amdgcn_global_load_lds((const __attribute__((address_space(1))) void*)g,
                                   (__attribute__((address_space(3))) void*)l, 16, 0, 0);
}

// ---------------- weight transpose + f32->bf16 convert ----------------
__global__ __launch_bounds__(256) void wconv(
    const float* __restrict__ Wq, const float* __restrict__ Wk,
    const float* __restrict__ Wv, const float* __restrict__ Wo,
    const float* __restrict__ Wi, const float* __restrict__ Wo2,
    bf16* __restrict__ wt)
{
  __shared__ float tile[32][33];
  const int bid = blockIdx.x;
  const float* src; bf16* dst; int K, N, tIdx;
  if (bid < 2304) {
    int m = bid / 576; tIdx = bid % 576; K = 768; N = 768;
    src = (m == 0) ? Wq : (m == 1) ? Wk : (m == 2) ? Wv : Wo;
    dst = wt + (size_t)m * 589824;
  } else if (bid < 4608) {
    tIdx = bid - 2304; K = 768; N = 3072; src = Wi; dst = wt + 2359296;
  } else {
    tIdx = bid - 4608; K = 3072; N = 768; src = Wo2; dst = wt + 4718592;
  }
  const int tilesN = N >> 5;
  const int tn = tIdx % tilesN, tk = tIdx / tilesN;
  const int n0 = tn * 32, k0 = tk * 32;
  const int tx = threadIdx.x & 31, ty = threadIdx.x >> 5;
#pragma unroll
  for (int r = 0; r < 4; ++r)
    tile[ty + r * 8][tx] = src[(size_t)(k0 + ty + r * 8) * N + n0 + tx];
  __syncthreads();
#pragma unroll
  for (int r = 0; r < 4; ++r)
    dst[(size_t)(n0 + ty + r * 8) * K + k0 + tx] = __float2bfloat16(tile[tx][ty + r * 8]);
}

// ---------------- GEMM: C = A[M,K](bf16) @ Bt[N,K]^T(bf16) + bias ----------------
// epi 0: fused QKV -> bf16; Q (mat==0) additionally scaled by 0.125
// epi 2: gelu(acc+bias) -> bf16
// epi 3: acc+bias -> f32
__global__ __launch_bounds__(256) void gemm_bf16(
    const bf16* __restrict__ A, const bf16* __restrict__ Bt,
    void* __restrict__ out, const float* __restrict__ b0,
    const float* __restrict__ b1, const float* __restrict__ b2,
    int M, int N, int K, int epi)
{
  __shared__ __align__(16) bf16 As[128 * 32];
  __shared__ __align__(16) bf16 Bs[128 * 32];
  const int m0 = blockIdx.y * 128;
  const int n0 = blockIdx.x * 128;
  const int t = threadIdx.x;
  const int lane = t & 63;
  const int w = t >> 6;
  const int wr = w >> 1, wc = w & 1;

  f32x4 acc[4][4];
#pragma unroll
  for (int i = 0; i < 4; ++i)
#pragma unroll
    for (int j = 0; j < 4; ++j) acc[i][j] = (f32x4)0.f;

  const int idx = t * 8;
  const int rowA = idx >> 5;
  const int colA = idx & 31;
  const bf16* gA = A + (size_t)(m0 + rowA) * K + colA;
  const bf16* gB = Bt + (size_t)(n0 + rowA) * K + colA;
  const int kofs = (lane >> 4) * 8;
  const int fr = lane & 15;

  for (int k0 = 0; k0 < K; k0 += 32) {
    gload16(gA + k0, As + idx);
    gload16(gA + k0 + (size_t)64 * K, As + idx + 2048);
    gload16(gB + k0, Bs + idx);
    gload16(gB + k0 + (size_t)64 * K, Bs + idx + 2048);
    __syncthreads();
    bf16x8 af[4], bfr[4];
#pragma unroll
    for (int m = 0; m < 4; ++m)
      af[m] = *(const bf16x8*)(As + (wr * 64 + m * 16 + fr) * 32 + kofs);
#pragma unroll
    for (int n = 0; n < 4; ++n)
      bfr[n] = *(const bf16x8*)(Bs + (wc * 64 + n * 16 + fr) * 32 + kofs);
#pragma unroll
    for (int m = 0; m < 4; ++m)
#pragma unroll
      for (int n = 0; n < 4; ++n)
        acc[m][n] = __builtin_amdgcn_mfma_f32_16x16x32_bf16(af[m], bfr[n], acc[m][n], 0, 0, 0);
    __syncthreads();
  }

  const int rr = (lane >> 4) * 4;
  const int cc0 = lane & 15;
  if (epi == 0) {
    const int mat = n0 / HDIM;
    const float* bias = (mat == 0) ? b0 : (mat == 1) ? b1 : b2;
    const float qs = (mat == 0) ? 0.125f : 1.0f;
    bf16* dst = (bf16*)out + (size_t)mat * MROWS * HDIM;
    const int nl = n0 - mat * HDIM;
#pragma unroll
    for (int m = 0; m < 4; ++m)
#pragma unroll
      for (int n = 0; n < 4; ++n) {
        const int row = m0 + wr * 64 + m * 16 + rr;
        const int col = nl + wc * 64 + n * 16 + cc0;
        const float bv = bias[col];
#pragma unroll
        for (int r = 0; r < 4; ++r)
          dst[(size_t)(row + r) * HDIM + col] = __float2bfloat16((acc[m][n][r] + bv) * qs);
      }
  } else if (epi == 2) {
    bf16* dst = (bf16*)out;
#pragma unroll
    for (int m = 0; m < 4; ++m)
#pragma unroll
      for (int n = 0; n < 4; ++n) {
        const int row = m0 + wr * 64 + m * 16 + rr;
        const int col = n0 + wc * 64 + n * 16 + cc0;
        const float bv = b0[col];
#pragma unroll
        for (int r = 0; r < 4; ++r) {
          float v = acc[m][n][r] + bv;
          v = 0.5f * v * (1.0f + erff(v * 0.70710678118654752f));
          dst[(size_t)(row + r) * N + col] = __float2bfloat16(v);
        }
      }
  } else {
    float* dst = (float*)out;
#pragma unroll
    for (int m = 0; m < 4; ++m)
#pragma unroll
      for (int n = 0; n < 4; ++n) {
        const int row = m0 + wr * 64 + m * 16 + rr;
        const int col = n0 + wc * 64 + n * 16 + cc0;
        const float bv = b0[col];
#pragma unroll
        for (int r = 0; r < 4; ++r)
          dst[(size_t)(row + r) * N + col] = acc[m][n][r] + bv;
      }
  }
}

// ---------------- MFMA sliding-window attention ----------------
// grid (chunk=6, head=12, batch=8), 256 threads = 4 waves x 32 queries.
// S^T = mfma(K, Q): C/D col = query (lane&15), row = key ((lane>>4)*4+reg).
// O^T = mfma(V^T, P^T): V^T staged swizzled in LDS; P via wave-private LDS.
__global__ __launch_bounds__(256) void attn_mfma(
    const bf16* __restrict__ qkv, bf16* __restrict__ attb)
{
  const int c = blockIdx.x, h = blockIdx.y, b = blockIdx.z;
  __shared__ unsigned int Vtw[64 * 64];           // V^T [d=64][key=128] bf16, swizzled (16KB)
  __shared__ __align__(16) bf16 Pl[4][32 * 40];   // per-wave P [query=32][key=32], stride 40
  const int t = threadIdx.x;
  const int lane = t & 63;
  const int w = t >> 6;
  const int fr = lane & 15;
  const int g = lane >> 4;
  const bf16* Km = qkv + (size_t)4718592;
  const bf16* Vm = qkv + (size_t)9437184;
  const size_t qrow0 = (size_t)(b * 768 + c * 128);

  // Q fragments (B-operand): col = query = nt*16+fr, k = d = ks*32 + g*8 .. +7
  bf16x8 qf[2][2];
#pragma unroll
  for (int nt = 0; nt < 2; ++nt)
#pragma unroll
    for (int ks = 0; ks < 2; ++ks)
      qf[nt][ks] = *(const bf16x8*)(qkv + (qrow0 + w * 32 + nt * 16 + fr) * HDIM + h * 64 + ks * 32 + g * 8);

  f32x4 oacc[4][2];
#pragma unroll
  for (int i = 0; i < 4; ++i) { oacc[i][0] = (f32x4)0.f; oacc[i][1] = (f32x4)0.f; }
  float mrun[2] = {-1e30f, -1e30f};
  float lrun[2] = {0.f, 0.f};

#pragma unroll 1
  for (int cc = c - 1; cc <= c + 1; ++cc) {
    if (cc < 0 || cc >= NCHUNK) continue;          // uniform (blockIdx-based)
    __syncthreads();                                // protect Vtw from prior readers
    {
      // stage V^T swizzled: thread handles d-range (t&7)*8..+8, key pairs
      const int d0 = (t & 7) * 8;
#pragma unroll
      for (int half = 0; half < 2; ++half) {
        const int kp2 = (t >> 3) + half * 32;       // key-pair 0..63
        const bf16* vr = Vm + ((size_t)(b * 768 + cc * 128) + kp2 * 2) * HDIM + h * 64 + d0;
        uint4 r0 = *(const uint4*)vr;
        uint4 r1 = *(const uint4*)(vr + HDIM);
        unsigned int a0[4] = {r0.x, r0.y, r0.z, r0.w};
        unsigned int a1[4] = {r1.x, r1.y, r1.z, r1.w};
#pragma unroll
        for (int e = 0; e < 8; ++e) {
          const int d = d0 + e;
          unsigned int lo = (a0[e >> 1] >> ((e & 1) * 16)) & 0xffffu;
          unsigned int hi = (a1[e >> 1] >> ((e & 1) * 16)) & 0xffffu;
          unsigned int byteoff = (unsigned int)(d * 256 + kp2 * 4);
          byteoff ^= ((((d >> 3) ^ d) & 7) << 4);
          Vtw[byteoff >> 2] = lo | (hi << 16);
        }
      }
    }
    __syncthreads();
    const int mode = (cc < c) ? 0 : (cc == c ? 1 : 2);
    const bf16* Kc = Km + ((size_t)(b * 768 + cc * 128)) * HDIM + h * 64;

#pragma unroll 1
    for (int kb = 0; kb < 4; ++kb) {
      // --- QK^T: S^T tile [32 keys][32 queries] ---
      f32x4 sacc[2][2];
      sacc[0][0] = sacc[0][1] = sacc[1][0] = sacc[1][1] = (f32x4)0.f;
#pragma unroll
      for (int ks = 0; ks < 2; ++ks)
#pragma unroll
        for (int mt = 0; mt < 2; ++mt) {
          bf16x8 kf = *(const bf16x8*)(Kc + (size_t)(kb * 32 + mt * 16 + fr) * HDIM + ks * 32 + g * 8);
          sacc[mt][0] = __builtin_amdgcn_mfma_f32_16x16x32_bf16(kf, qf[0][ks], sacc[mt][0], 0, 0, 0);
          sacc[mt][1] = __builtin_amdgcn_mfma_f32_16x16x32_bf16(kf, qf[1][ks], sacc[mt][1], 0, 0, 0);
        }
      // --- mask + online softmax (per query = col) ---
#pragma unroll
      for (int nt = 0; nt < 2; ++nt) {
        const int iq = w * 32 + nt * 16 + fr;
        float pm = -1e30f;
#pragma unroll
        for (int mt = 0; mt < 2; ++mt)
#pragma unroll
          for (int r = 0; r < 4; ++r) {
            const int j = kb * 32 + mt * 16 + g * 4 + r;
            const bool valid = (mode == 1) || (mode == 0 ? (j >= iq) : (j <= iq));
            const float sv = valid ? sacc[mt][nt][r] : -1e30f;
            sacc[mt][nt][r] = sv;
            pm = fmaxf(pm, sv);
          }
        pm = fmaxf(pm, __shfl_xor(pm, 16));
        pm = fmaxf(pm, __shfl_xor(pm, 32));
        const float mnew = fmaxf(fmaxf(mrun[nt], pm), -1e20f);
        const float sc = __expf(mrun[nt] - mnew);
        mrun[nt] = mnew;
        lrun[nt] *= sc;
#pragma unroll
        for (int mt = 0; mt < 4; ++mt) oacc[mt][nt] *= sc;
        float ps = 0.f;
#pragma unroll
        for (int mt = 0; mt < 2; ++mt) {
          union { bf16 hh[4]; uint2 uu; } pk;
#pragma unroll
          for (int r = 0; r < 4; ++r) {
            const float p = __expf(sacc[mt][nt][r] - mnew);
            ps += p;
            pk.hh[r] = __float2bfloat16(p);
          }
          *(uint2*)(&Pl[w][(nt * 16 + fr) * 40 + mt * 16 + g * 4]) = pk.uu;
        }
        ps += __shfl_xor(ps, 16);
        ps += __shfl_xor(ps, 32);
        lrun[nt] += ps;
      }
      // --- PV: O^T += V^T · P^T ---
      bf16x8 bpf[2];
#pragma unroll
      for (int nt = 0; nt < 2; ++nt)
        bpf[nt] = *(const bf16x8*)(&Pl[w][(nt * 16 + fr) * 40 + g * 8]);
#pragma unroll
      for (int mt = 0; mt < 4; ++mt) {
        const int d = mt * 16 + fr;
        unsigned int byteoff = (unsigned int)(d * 256 + kb * 64 + g * 16);
        byteoff ^= ((((d >> 3) ^ d) & 7) << 4);
        bf16x8 vf = *(const bf16x8*)((const char*)Vtw + byteoff);
        oacc[mt][0] = __builtin_amdgcn_mfma_f32_16x16x32_bf16(vf, bpf[0], oacc[mt][0], 0, 0, 0);
        oacc[mt][1] = __builtin_amdgcn_mfma_f32_16x16x32_bf16(vf, bpf[1], oacc[mt][1], 0, 0, 0);
      }
    }
  }
  // --- epilogue: O^T C/D col=query, row=d ---
#pragma unroll
  for (int nt = 0; nt < 2; ++nt) {
    const float rl = 1.f / lrun[nt];
    bf16* orow = attb + (qrow0 + w * 32 + nt * 16 + fr) * HDIM + h * 64;
#pragma unroll
    for (int mt = 0; mt < 4; ++mt) {
      union { bf16 hh[4]; uint2 uu; } ok;
#pragma unroll
      for (int r = 0; r < 4; ++r) ok.hh[r] = __float2bfloat16(oacc[mt][nt][r] * rl);
      *(uint2*)(orow + mt * 16 + g * 4) = ok.uu;
    }
  }
}

// ---------------- LayerNorm kernels ----------------
__device__ __forceinline__ void blk_reduce2(float& s1, float& s2) {
#pragma unroll
  for (int o = 32; o > 0; o >>= 1) { s1 += __shfl_xor(s1, o); s2 += __shfl_xor(s2, o); }
  __shared__ float red[8];
  const int w = threadIdx.x >> 6;
  if ((threadIdx.x & 63) == 0) { red[w] = s1; red[4 + w] = s2; }
  __syncthreads();
  s1 = red[0] + red[1] + red[2] + red[3];
  s2 = red[4] + red[5] + red[6] + red[7];
}

__global__ __launch_bounds__(256) void embed_ln(
    const float* __restrict__ emb, const float* __restrict__ pos,
    const float* __restrict__ tte, const float* __restrict__ g,
    const float* __restrict__ bt, float* __restrict__ x, bf16* __restrict__ xb)
{
  const int row = blockIdx.x;
  const int s = row % 768;
  const int t = threadIdx.x;
  const size_t base = (size_t)row * HDIM;
  const size_t pbase = (size_t)(s + 2) * HDIM;
  float v[3];
#pragma unroll
  for (int i = 0; i < 3; ++i) {
    const int idx = t + i * 256;
    v[i] = emb[base + idx] + pos[pbase + idx] + tte[idx];
  }
  float s1 = v[0] + v[1] + v[2];
  float s2 = v[0]*v[0] + v[1]*v[1] + v[2]*v[2];
  blk_reduce2(s1, s2);
  const float mu = s1 * (1.f / 768.f);
  const float var = s2 * (1.f / 768.f) - mu * mu;
  const float inv = rsqrtf(var + 1e-12f);
#pragma unroll
  for (int i = 0; i < 3; ++i) {
    const int idx = t + i * 256;
    const float o = (v[i] - mu) * inv * g[idx] + bt[idx];
    x[base + idx] = o;
    xb[base + idx] = __float2bfloat16(o);
  }
}

__global__ __launch_bounds__(256) void add_ln(
    const float* __restrict__ tmp, float* __restrict__ x, bf16* __restrict__ xb,
    const float* __restrict__ g, const float* __restrict__ bt)
{
  const int row = blockIdx.x;
  const int t = threadIdx.x;
  const size_t base = (size_t)row * HDIM;
  float v[3];
#pragma unroll
  for (int i = 0; i < 3; ++i) {
    const int idx = t + i * 256;
    v[i] = x[base + idx] + tmp[base + idx];
  }
  float s1 = v[0] + v[1] + v[2];
  float s2 = v[0]*v[0] + v[1]*v[1] + v[2]*v[2];
  blk_reduce2(s1, s2);
  const float mu = s1 * (1.f / 768.f);
  const float var = s2 * (1.f / 768.f) - mu * mu;
  const float inv = rsqrtf(var + 1e-12f);
#pragma unroll
  for (int i = 0; i < 3; ++i) {
    const int idx = t + i * 256;
    const float o = (v[i] - mu) * inv * g[idx] + bt[idx];
    x[base + idx] = o;
    xb[base + idx] = __float2bfloat16(o);
  }
}

// ---------------- gate ----------------
__global__ __launch_bounds__(256) void gate_kernel(
    const float* __restrict__ x, const float* __restrict__ gw,
    const float* __restrict__ gb, float* __restrict__ out)
{
  const int row = blockIdx.x * 4 + (threadIdx.x >> 6);
  const int lane = threadIdx.x & 63;
  const float* xr = x + (size_t)row * HDIM;
  float s = 0.f;
#pragma unroll
  for (int i = 0; i < 12; ++i) s += xr[lane + i * 64] * gw[lane + i * 64];
#pragma unroll
  for (int o = 32; o > 0; o >>= 1) s += __shfl_xor(s, o);
  if (lane == 0) out[row] = s + gb[0];
}

// ---------------- host ----------------
extern "C" void kernel_launch(void* const* d_in, const int* in_sizes, int n_in,
                              void* d_out, int out_size, void* d_ws, size_t ws_size,
                              hipStream_t stream)
{
  const float* emb = (const float*)d_in[0];
  const float* pos = (const float*)d_in[2];
  const float* tte = (const float*)d_in[3];
  const float* eg  = (const float*)d_in[4];
  const float* eb  = (const float*)d_in[5];
  const float* Wq  = (const float*)d_in[6];
  const float* bq  = (const float*)d_in[7];
  const float* Wk  = (const float*)d_in[8];
  const float* bk  = (const float*)d_in[9];
  const float* Wv  = (const float*)d_in[10];
  const float* bv  = (const float*)d_in[11];
  const float* Wo  = (const float*)d_in[12];
  const float* bo  = (const float*)d_in[13];
  const float* g1  = (const float*)d_in[14];
  const float* be1 = (const float*)d_in[15];
  const float* Wi  = (const float*)d_in[16];
  const float* bi  = (const float*)d_in[17];
  const float* Wo2 = (const float*)d_in[18];
  const float* bo2 = (const float*)d_in[19];
  const float* g2  = (const float*)d_in[20];
  const float* be2 = (const float*)d_in[21];
  const float* gw  = (const float*)d_in[22];
  const float* gb  = (const float*)d_in[23];

  char* wsp = (char*)d_ws;
  bf16* wt   = (bf16*)wsp;
  bf16* xb   = (bf16*)(wsp + 14155776);
  bf16* qkvb = (bf16*)(wsp + 23592960);
  float* tmp = (float*)(wsp + 61341696);
  bf16* attb = qkvb + (size_t)3 * 4718592;
  bf16* ffb  = qkvb;                 // alias: q/k/v/att dead when FFN1 runs
  float* x   = (float*)d_out;        // f32 residual stream lives in d_out
  float* gate = x + 4718592;

  embed_ln<<<6144, 256, 0, stream>>>(emb, pos, tte, eg, eb, x, xb);

  for (int l = 0; l < 12; ++l) {
    wconv<<<6912, 256, 0, stream>>>(Wq + (size_t)l * 589824, Wk + (size_t)l * 589824,
                                    Wv + (size_t)l * 589824, Wo + (size_t)l * 589824,
                                    Wi + (size_t)l * 2359296, Wo2 + (size_t)l * 2359296, wt);
    gemm_bf16<<<dim3(18, 48), 256, 0, stream>>>(xb, wt, qkvb,
        bq + l * 768, bk + l * 768, bv + l * 768, 6144, 2304, 768, 0);
    attn_mfma<<<dim3(6, 12, 8), 256, 0, stream>>>(qkvb, attb);
    gemm_bf16<<<dim3(6, 48), 256, 0, stream>>>(attb, wt + 1769472, tmp,
        bo + l * 768, nullptr, nullptr, 6144, 768, 768, 3);
    add_ln<<<6144, 256, 0, stream>>>(tmp, x, xb, g1 + l * 768, be1 + l * 768);
    gemm_bf16<<<dim3(24, 48), 256, 0, stream>>>(xb, wt + 2359296, ffb,
        bi + l * 3072, nullptr, nullptr, 6144, 3072, 768, 2);
    gemm_bf16<<<dim3(6, 48), 256, 0, stream>>>(ffb, wt + 4718592, tmp,
        bo2 + l * 768, nullptr, nullptr, 6144, 768, 3072, 3);
    add_ln<<<6144, 256, 0, stream>>>(tmp, x, xb, g2 + l * 768, be2 + l * 768);
  }

  gate_kernel<<<1536, 256, 0, stream>>>(x, gw, gb, gate);
}

// Round 3
// 3714.639 us; speedup vs baseline: 3.5529x; 1.0224x over previous
//
#include <hip/hip_runtime.h>
#include <hip/hip_bf16.h>
#include <math.h>

typedef __hip_bfloat16 bf16;
typedef __attribute__((ext_vector_type(8))) __bf16 bf16x8;
typedef __attribute__((ext_vector_type(4))) float f32x4;

#define HDIM 768
#define MROWS 6144
#define NCHUNK 6

__device__ __forceinline__ float bf2f(unsigned int u) {
  union { unsigned int i; float f; } c; c.i = u << 16; return c.f;
}

__device__ __forceinline__ void gload16(const void* g, void* l) {
  __builtin_amdgcn_global_load_lds((const __attribute__((address_space(1))) void*)g,
                                   (__attribute__((address_space(3))) void*)l, 16, 0, 0);
}

// overflow-safe tanh-approx GELU (error ~1e-3 abs, well under threshold slack)
__device__ __forceinline__ float gelu_f(float v) {
  const float u2 = 1.5957691216057308f * (v + 0.044715f * v * v * v); // 2*0.79788456*(...)
  const float e = __expf(u2);
  const float th = 1.f - 2.f / (e + 1.f);   // = tanh(u); safe at e->inf / e->0
  return 0.5f * v * (1.f + th);
}

// ---------------- weight transpose + f32->bf16 convert ----------------
__global__ __launch_bounds__(256) void wconv(
    const float* __restrict__ Wq, const float* __restrict__ Wk,
    const float* __restrict__ Wv, const float* __restrict__ Wo,
    const float* __restrict__ Wi, const float* __restrict__ Wo2,
    bf16* __restrict__ wt)
{
  __shared__ float tile[32][33];
  const int bid = blockIdx.x;
  const float* src; bf16* dst; int K, N, tIdx;
  if (bid < 2304) {
    int m = bid / 576; tIdx = bid % 576; K = 768; N = 768;
    src = (m == 0) ? Wq : (m == 1) ? Wk : (m == 2) ? Wv : Wo;
    dst = wt + (size_t)m * 589824;
  } else if (bid < 4608) {
    tIdx = bid - 2304; K = 768; N = 3072; src = Wi; dst = wt + 2359296;
  } else {
    tIdx = bid - 4608; K = 3072; N = 768; src = Wo2; dst = wt + 4718592;
  }
  const int tilesN = N >> 5;
  const int tn = tIdx % tilesN, tk = tIdx / tilesN;
  const int n0 = tn * 32, k0 = tk * 32;
  const int tx = threadIdx.x & 31, ty = threadIdx.x >> 5;
#pragma unroll
  for (int r = 0; r < 4; ++r)
    tile[ty + r * 8][tx] = src[(size_t)(k0 + ty + r * 8) * N + n0 + tx];
  __syncthreads();
#pragma unroll
  for (int r = 0; r < 4; ++r)
    dst[(size_t)(n0 + ty + r * 8) * K + k0 + tx] = __float2bfloat16(tile[tx][ty + r * 8]);
}

// ---------------- GEMM: C = A[M,K](bf16) @ Bt[N,K]^T(bf16) + bias ----------------
// 2-phase double-buffered pipeline (T3-minimum): stage t+1, compute t, one barrier/iter.
// epi 0: fused QKV -> bf16; Q (mat==0) additionally scaled by 0.125
// epi 2: gelu(acc+bias) -> bf16
// epi 3: acc+bias -> f32
__global__ __launch_bounds__(256) void gemm_bf16(
    const bf16* __restrict__ A, const bf16* __restrict__ Bt,
    void* __restrict__ out, const float* __restrict__ b0,
    const float* __restrict__ b1, const float* __restrict__ b2,
    int M, int N, int K, int epi)
{
  __shared__ __align__(16) bf16 As[2][128 * 32];
  __shared__ __align__(16) bf16 Bs[2][128 * 32];
  const int m0 = blockIdx.y * 128;
  const int n0 = blockIdx.x * 128;
  const int t = threadIdx.x;
  const int lane = t & 63;
  const int w = t >> 6;
  const int wr = w >> 1, wc = w & 1;

  f32x4 acc[4][4];
#pragma unroll
  for (int i = 0; i < 4; ++i)
#pragma unroll
    for (int j = 0; j < 4; ++j) acc[i][j] = (f32x4)0.f;

  const int idx = t * 8;
  const int rowA = idx >> 5;
  const int colA = idx & 31;
  const bf16* gA = A + (size_t)(m0 + rowA) * K + colA;
  const bf16* gB = Bt + (size_t)(n0 + rowA) * K + colA;
  const int kofs = (lane >> 4) * 8;
  const int fr = lane & 15;
  const int nt = K >> 5;

  // prologue: stage tile 0 into buf 0
  gload16(gA, As[0] + idx);
  gload16(gA + (size_t)64 * K, As[0] + idx + 2048);
  gload16(gB, Bs[0] + idx);
  gload16(gB + (size_t)64 * K, Bs[0] + idx + 2048);
  __syncthreads();

  int cur = 0;
#pragma unroll 1
  for (int kt = 0; kt < nt - 1; ++kt) {
    // stage tile kt+1 into the other buffer (latency hides under compute below)
    const int k0 = (kt + 1) << 5;
    const int nxt = cur ^ 1;
    gload16(gA + k0, As[nxt] + idx);
    gload16(gA + k0 + (size_t)64 * K, As[nxt] + idx + 2048);
    gload16(gB + k0, Bs[nxt] + idx);
    gload16(gB + k0 + (size_t)64 * K, Bs[nxt] + idx + 2048);
    // compute tile kt from current buffer
    bf16x8 af[4], bfr[4];
#pragma unroll
    for (int m = 0; m < 4; ++m)
      af[m] = *(const bf16x8*)(As[cur] + (wr * 64 + m * 16 + fr) * 32 + kofs);
#pragma unroll
    for (int n = 0; n < 4; ++n)
      bfr[n] = *(const bf16x8*)(Bs[cur] + (wc * 64 + n * 16 + fr) * 32 + kofs);
#pragma unroll
    for (int m = 0; m < 4; ++m)
#pragma unroll
      for (int n = 0; n < 4; ++n)
        acc[m][n] = __builtin_amdgcn_mfma_f32_16x16x32_bf16(af[m], bfr[n], acc[m][n], 0, 0, 0);
    __syncthreads();   // drains stage loads; all waves done reading As[cur]
    cur ^= 1;
  }
  { // epilogue tile (no prefetch)
    bf16x8 af[4], bfr[4];
#pragma unroll
    for (int m = 0; m < 4; ++m)
      af[m] = *(const bf16x8*)(As[cur] + (wr * 64 + m * 16 + fr) * 32 + kofs);
#pragma unroll
    for (int n = 0; n < 4; ++n)
      bfr[n] = *(const bf16x8*)(Bs[cur] + (wc * 64 + n * 16 + fr) * 32 + kofs);
#pragma unroll
    for (int m = 0; m < 4; ++m)
#pragma unroll
      for (int n = 0; n < 4; ++n)
        acc[m][n] = __builtin_amdgcn_mfma_f32_16x16x32_bf16(af[m], bfr[n], acc[m][n], 0, 0, 0);
  }

  const int rr = (lane >> 4) * 4;
  const int cc0 = lane & 15;
  if (epi == 0) {
    const int mat = n0 / HDIM;
    const float* bias = (mat == 0) ? b0 : (mat == 1) ? b1 : b2;
    const float qs = (mat == 0) ? 0.125f : 1.0f;
    bf16* dst = (bf16*)out + (size_t)mat * MROWS * HDIM;
    const int nl = n0 - mat * HDIM;
#pragma unroll
    for (int m = 0; m < 4; ++m)
#pragma unroll
      for (int n = 0; n < 4; ++n) {
        const int row = m0 + wr * 64 + m * 16 + rr;
        const int col = nl + wc * 64 + n * 16 + cc0;
        const float bv = bias[col];
#pragma unroll
        for (int r = 0; r < 4; ++r)
          dst[(size_t)(row + r) * HDIM + col] = __float2bfloat16((acc[m][n][r] + bv) * qs);
      }
  } else if (epi == 2) {
    bf16* dst = (bf16*)out;
#pragma unroll
    for (int m = 0; m < 4; ++m)
#pragma unroll
      for (int n = 0; n < 4; ++n) {
        const int row = m0 + wr * 64 + m * 16 + rr;
        const int col = n0 + wc * 64 + n * 16 + cc0;
        const float bv = b0[col];
#pragma unroll
        for (int r = 0; r < 4; ++r)
          dst[(size_t)(row + r) * N + col] = __float2bfloat16(gelu_f(acc[m][n][r] + bv));
      }
  } else {
    float* dst = (float*)out;
#pragma unroll
    for (int m = 0; m < 4; ++m)
#pragma unroll
      for (int n = 0; n < 4; ++n) {
        const int row = m0 + wr * 64 + m * 16 + rr;
        const int col = n0 + wc * 64 + n * 16 + cc0;
        const float bv = b0[col];
#pragma unroll
        for (int r = 0; r < 4; ++r)
          dst[(size_t)(row + r) * N + col] = acc[m][n][r] + bv;
      }
  }
}

// ---------------- MFMA sliding-window attention ----------------
__global__ __launch_bounds__(256) void attn_mfma(
    const bf16* __restrict__ qkv, bf16* __restrict__ attb)
{
  const int c = blockIdx.x, h = blockIdx.y, b = blockIdx.z;
  __shared__ unsigned int Vtw[64 * 64];           // V^T [d=64][key=128] bf16, swizzled (16KB)
  __shared__ __align__(16) bf16 Pl[4][32 * 40];   // per-wave P [query=32][key=32], stride 40
  const int t = threadIdx.x;
  const int lane = t & 63;
  const int w = t >> 6;
  const int fr = lane & 15;
  const int g = lane >> 4;
  const bf16* Km = qkv + (size_t)4718592;
  const bf16* Vm = qkv + (size_t)9437184;
  const size_t qrow0 = (size_t)(b * 768 + c * 128);

  bf16x8 qf[2][2];
#pragma unroll
  for (int nt = 0; nt < 2; ++nt)
#pragma unroll
    for (int ks = 0; ks < 2; ++ks)
      qf[nt][ks] = *(const bf16x8*)(qkv + (qrow0 + w * 32 + nt * 16 + fr) * HDIM + h * 64 + ks * 32 + g * 8);

  f32x4 oacc[4][2];
#pragma unroll
  for (int i = 0; i < 4; ++i) { oacc[i][0] = (f32x4)0.f; oacc[i][1] = (f32x4)0.f; }
  float mrun[2] = {-1e30f, -1e30f};
  float lrun[2] = {0.f, 0.f};

#pragma unroll 1
  for (int cc = c - 1; cc <= c + 1; ++cc) {
    if (cc < 0 || cc >= NCHUNK) continue;
    __syncthreads();
    {
      const int d0 = (t & 7) * 8;
#pragma unroll
      for (int half = 0; half < 2; ++half) {
        const int kp2 = (t >> 3) + half * 32;
        const bf16* vr = Vm + ((size_t)(b * 768 + cc * 128) + kp2 * 2) * HDIM + h * 64 + d0;
        uint4 r0 = *(const uint4*)vr;
        uint4 r1 = *(const uint4*)(vr + HDIM);
        unsigned int a0[4] = {r0.x, r0.y, r0.z, r0.w};
        unsigned int a1[4] = {r1.x, r1.y, r1.z, r1.w};
#pragma unroll
        for (int e = 0; e < 8; ++e) {
          const int d = d0 + e;
          unsigned int lo = (a0[e >> 1] >> ((e & 1) * 16)) & 0xffffu;
          unsigned int hi = (a1[e >> 1] >> ((e & 1) * 16)) & 0xffffu;
          unsigned int byteoff = (unsigned int)(d * 256 + kp2 * 4);
          byteoff ^= ((((d >> 3) ^ d) & 7) << 4);
          Vtw[byteoff >> 2] = lo | (hi << 16);
        }
      }
    }
    __syncthreads();
    const int mode = (cc < c) ? 0 : (cc == c ? 1 : 2);
    const bf16* Kc = Km + ((size_t)(b * 768 + cc * 128)) * HDIM + h * 64;

#pragma unroll 1
    for (int kb = 0; kb < 4; ++kb) {
      f32x4 sacc[2][2];
      sacc[0][0] = sacc[0][1] = sacc[1][0] = sacc[1][1] = (f32x4)0.f;
#pragma unroll
      for (int ks = 0; ks < 2; ++ks)
#pragma unroll
        for (int mt = 0; mt < 2; ++mt) {
          bf16x8 kf = *(const bf16x8*)(Kc + (size_t)(kb * 32 + mt * 16 + fr) * HDIM + ks * 32 + g * 8);
          sacc[mt][0] = __builtin_amdgcn_mfma_f32_16x16x32_bf16(kf, qf[0][ks], sacc[mt][0], 0, 0, 0);
          sacc[mt][1] = __builtin_amdgcn_mfma_f32_16x16x32_bf16(kf, qf[1][ks], sacc[mt][1], 0, 0, 0);
        }
#pragma unroll
      for (int nt = 0; nt < 2; ++nt) {
        const int iq = w * 32 + nt * 16 + fr;
        float pm = -1e30f;
#pragma unroll
        for (int mt = 0; mt < 2; ++mt)
#pragma unroll
          for (int r = 0; r < 4; ++r) {
            const int j = kb * 32 + mt * 16 + g * 4 + r;
            const bool valid = (mode == 1) || (mode == 0 ? (j >= iq) : (j <= iq));
            const float sv = valid ? sacc[mt][nt][r] : -1e30f;
            sacc[mt][nt][r] = sv;
            pm = fmaxf(pm, sv);
          }
        pm = fmaxf(pm, __shfl_xor(pm, 16));
        pm = fmaxf(pm, __shfl_xor(pm, 32));
        const float mnew = fmaxf(fmaxf(mrun[nt], pm), -1e20f);
        const float sc = __expf(mrun[nt] - mnew);
        mrun[nt] = mnew;
        lrun[nt] *= sc;
#pragma unroll
        for (int mt = 0; mt < 4; ++mt) oacc[mt][nt] *= sc;
        float ps = 0.f;
#pragma unroll
        for (int mt = 0; mt < 2; ++mt) {
          union { bf16 hh[4]; uint2 uu; } pk;
#pragma unroll
          for (int r = 0; r < 4; ++r) {
            const float p = __expf(sacc[mt][nt][r] - mnew);
            ps += p;
            pk.hh[r] = __float2bfloat16(p);
          }
          *(uint2*)(&Pl[w][(nt * 16 + fr) * 40 + mt * 16 + g * 4]) = pk.uu;
        }
        ps += __shfl_xor(ps, 16);
        ps += __shfl_xor(ps, 32);
        lrun[nt] += ps;
      }
      bf16x8 bpf[2];
#pragma unroll
      for (int nt = 0; nt < 2; ++nt)
        bpf[nt] = *(const bf16x8*)(&Pl[w][(nt * 16 + fr) * 40 + g * 8]);
#pragma unroll
      for (int mt = 0; mt < 4; ++mt) {
        const int d = mt * 16 + fr;
        unsigned int byteoff = (unsigned int)(d * 256 + kb * 64 + g * 16);
        byteoff ^= ((((d >> 3) ^ d) & 7) << 4);
        bf16x8 vf = *(const bf16x8*)((const char*)Vtw + byteoff);
        oacc[mt][0] = __builtin_amdgcn_mfma_f32_16x16x32_bf16(vf, bpf[0], oacc[mt][0], 0, 0, 0);
        oacc[mt][1] = __builtin_amdgcn_mfma_f32_16x16x32_bf16(vf, bpf[1], oacc[mt][1], 0, 0, 0);
      }
    }
  }
#pragma unroll
  for (int nt = 0; nt < 2; ++nt) {
    const float rl = 1.f / lrun[nt];
    bf16* orow = attb + (qrow0 + w * 32 + nt * 16 + fr) * HDIM + h * 64;
#pragma unroll
    for (int mt = 0; mt < 4; ++mt) {
      union { bf16 hh[4]; uint2 uu; } ok;
#pragma unroll
      for (int r = 0; r < 4; ++r) ok.hh[r] = __float2bfloat16(oacc[mt][nt][r] * rl);
      *(uint2*)(orow + mt * 16 + g * 4) = ok.uu;
    }
  }
}

// ---------------- LayerNorm kernels ----------------
__device__ __forceinline__ void blk_reduce2(float& s1, float& s2) {
#pragma unroll
  for (int o = 32; o > 0; o >>= 1) { s1 += __shfl_xor(s1, o); s2 += __shfl_xor(s2, o); }
  __shared__ float red[8];
  const int w = threadIdx.x >> 6;
  if ((threadIdx.x & 63) == 0) { red[w] = s1; red[4 + w] = s2; }
  __syncthreads();
  s1 = red[0] + red[1] + red[2] + red[3];
  s2 = red[4] + red[5] + red[6] + red[7];
}

__global__ __launch_bounds__(256) void embed_ln(
    const float* __restrict__ emb, const float* __restrict__ pos,
    const float* __restrict__ tte, const float* __restrict__ g,
    const float* __restrict__ bt, float* __restrict__ x, bf16* __restrict__ xb)
{
  const int row = blockIdx.x;
  const int s = row % 768;
  const int t = threadIdx.x;
  const size_t base = (size_t)row * HDIM;
  const size_t pbase = (size_t)(s + 2) * HDIM;
  float v[3];
#pragma unroll
  for (int i = 0; i < 3; ++i) {
    const int idx = t + i * 256;
    v[i] = emb[base + idx] + pos[pbase + idx] + tte[idx];
  }
  float s1 = v[0] + v[1] + v[2];
  float s2 = v[0]*v[0] + v[1]*v[1] + v[2]*v[2];
  blk_reduce2(s1, s2);
  const float mu = s1 * (1.f / 768.f);
  const float var = s2 * (1.f / 768.f) - mu * mu;
  const float inv = rsqrtf(var + 1e-12f);
#pragma unroll
  for (int i = 0; i < 3; ++i) {
    const int idx = t + i * 256;
    const float o = (v[i] - mu) * inv * g[idx] + bt[idx];
    x[base + idx] = o;
    xb[base + idx] = __float2bfloat16(o);
  }
}

__global__ __launch_bounds__(256) void add_ln(
    const float* __restrict__ tmp, float* __restrict__ x, bf16* __restrict__ xb,
    const float* __restrict__ g, const float* __restrict__ bt)
{
  const int row = blockIdx.x;
  const int t = threadIdx.x;
  const size_t base = (size_t)row * HDIM;
  float v[3];
#pragma unroll
  for (int i = 0; i < 3; ++i) {
    const int idx = t + i * 256;
    v[i] = x[base + idx] + tmp[base + idx];
  }
  float s1 = v[0] + v[1] + v[2];
  float s2 = v[0]*v[0] + v[1]*v[1] + v[2]*v[2];
  blk_reduce2(s1, s2);
  const float mu = s1 * (1.f / 768.f);
  const float var = s2 * (1.f / 768.f) - mu * mu;
  const float inv = rsqrtf(var + 1e-12f);
#pragma unroll
  for (int i = 0; i < 3; ++i) {
    const int idx = t + i * 256;
    const float o = (v[i] - mu) * inv * g[idx] + bt[idx];
    x[base + idx] = o;
    xb[base + idx] = __float2bfloat16(o);
  }
}

// ---------------- gate ----------------
__global__ __launch_bounds__(256) void gate_kernel(
    const float* __restrict__ x, const float* __restrict__ gw,
    const float* __restrict__ gb, float* __restrict__ out)
{
  const int row = blockIdx.x * 4 + (threadIdx.x >> 6);
  const int lane = threadIdx.x & 63;
  const float* xr = x + (size_t)row * HDIM;
  float s = 0.f;
#pragma unroll
  for (int i = 0; i < 12; ++i) s += xr[lane + i * 64] * gw[lane + i * 64];
#pragma unroll
  for (int o = 32; o > 0; o >>= 1) s += __shfl_xor(s, o);
  if (lane == 0) out[row] = s + gb[0];
}

// ---------------- host ----------------
extern "C" void kernel_launch(void* const* d_in, const int* in_sizes, int n_in,
                              void* d_out, int out_size, void* d_ws, size_t ws_size,
                              hipStream_t stream)
{
  const float* emb = (const float*)d_in[0];
  const float* pos = (const float*)d_in[2];
  const float* tte = (const float*)d_in[3];
  const float* eg  = (const float*)d_in[4];
  const float* eb  = (const float*)d_in[5];
  const float* Wq  = (const float*)d_in[6];
  const float* bq  = (const float*)d_in[7];
  const float* Wk  = (const float*)d_in[8];
  const float* bk  = (const float*)d_in[9];
  const float* Wv  = (const float*)d_in[10];
  const float* bv  = (const float*)d_in[11];
  const float* Wo  = (const float*)d_in[12];
  const float* bo  = (const float*)d_in[13];
  const float* g1  = (const float*)d_in[14];
  const float* be1 = (const float*)d_in[15];
  const float* Wi  = (const float*)d_in[16];
  const float* bi  = (const float*)d_in[17];
  const float* Wo2 = (const float*)d_in[18];
  const float* bo2 = (const float*)d_in[19];
  const float* g2  = (const float*)d_in[20];
  const float* be2 = (const float*)d_in[21];
  const float* gw  = (const float*)d_in[22];
  const float* gb  = (const float*)d_in[23];

  char* wsp = (char*)d_ws;
  bf16* wt   = (bf16*)wsp;
  bf16* xb   = (bf16*)(wsp + 14155776);
  bf16* qkvb = (bf16*)(wsp + 23592960);
  float* tmp = (float*)(wsp + 61341696);
  bf16* attb = qkvb + (size_t)3 * 4718592;
  bf16* ffb  = qkvb;                 // alias: q/k/v/att dead when FFN1 runs
  float* x   = (float*)d_out;        // f32 residual stream lives in d_out
  float* gate = x + 4718592;

  embed_ln<<<6144, 256, 0, stream>>>(emb, pos, tte, eg, eb, x, xb);

  for (int l = 0; l < 12; ++l) {
    wconv<<<6912, 256, 0, stream>>>(Wq + (size_t)l * 589824, Wk + (size_t)l * 589824,
                                    Wv + (size_t)l * 589824, Wo + (size_t)l * 589824,
                                    Wi + (size_t)l * 2359296, Wo2 + (size_t)l * 2359296, wt);
    gemm_bf16<<<dim3(18, 48), 256, 0, stream>>>(xb, wt, qkvb,
        bq + l * 768, bk + l * 768, bv + l * 768, 6144, 2304, 768, 0);
    attn_mfma<<<dim3(6, 12, 8), 256, 0, stream>>>(qkvb, attb);
    gemm_bf16<<<dim3(6, 48), 256, 0, stream>>>(attb, wt + 1769472, tmp,
        bo + l * 768, nullptr, nullptr, 6144, 768, 768, 3);
    add_ln<<<6144, 256, 0, stream>>>(tmp, x, xb, g1 + l * 768, be1 + l * 768);
    gemm_bf16<<<dim3(24, 48), 256, 0, stream>>>(xb, wt + 2359296, ffb,
        bi + l * 3072, nullptr, nullptr, 6144, 3072, 768, 2);
    gemm_bf16<<<dim3(6, 48), 256, 0, stream>>>(ffb, wt + 4718592, tmp,
        bo2 + l * 768, nullptr, nullptr, 6144, 768, 3072, 3);
    add_ln<<<6144, 256, 0, stream>>>(tmp, x, xb, g2 + l * 768, be2 + l * 768);
  }

  gate_kernel<<<1536, 256, 0, stream>>>(x, gw, gb, gate);
}

// Round 4
// 3048.528 us; speedup vs baseline: 4.3292x; 1.2185x over previous
//
#include <hip/hip_runtime.h>
#include <hip/hip_bf16.h>
#include <math.h>

typedef __hip_bfloat16 bf16;
typedef __attribute__((ext_vector_type(8))) __bf16 bf16x8;
typedef __attribute__((ext_vector_type(4))) float f32x4;

#define HDIM 768
#define MROWS 6144
#define NCHUNK 6

__device__ __forceinline__ float bf2f(unsigned int u) {
  union { unsigned int i; float f; } c; c.i = u << 16; return c.f;
}

__device__ __forceinline__ void gload16(const void* g, void* l) {
  __builtin_amdgcn_global_load_lds((const __attribute__((address_space(1))) void*)g,
                                   (__attribute__((address_space(3))) void*)l, 16, 0, 0);
}

// overflow-safe tanh-approx GELU (error ~1e-3 abs)
__device__ __forceinline__ float gelu_f(float v) {
  const float u2 = 1.5957691216057308f * (v + 0.044715f * v * v * v);
  const float e = __expf(u2);
  const float th = 1.f - 2.f / (e + 1.f);
  return 0.5f * v * (1.f + th);
}

// ---------------- weight transpose + f32->bf16 convert ----------------
__global__ __launch_bounds__(256) void wconv(
    const float* __restrict__ Wq, const float* __restrict__ Wk,
    const float* __restrict__ Wv, const float* __restrict__ Wo,
    const float* __restrict__ Wi, const float* __restrict__ Wo2,
    bf16* __restrict__ wt)
{
  __shared__ float tile[32][33];
  const int bid = blockIdx.x;
  const float* src; bf16* dst; int K, N, tIdx;
  if (bid < 2304) {
    int m = bid / 576; tIdx = bid % 576; K = 768; N = 768;
    src = (m == 0) ? Wq : (m == 1) ? Wk : (m == 2) ? Wv : Wo;
    dst = wt + (size_t)m * 589824;
  } else if (bid < 4608) {
    tIdx = bid - 2304; K = 768; N = 3072; src = Wi; dst = wt + 2359296;
  } else {
    tIdx = bid - 4608; K = 3072; N = 768; src = Wo2; dst = wt + 4718592;
  }
  const int tilesN = N >> 5;
  const int tn = tIdx % tilesN, tk = tIdx / tilesN;
  const int n0 = tn * 32, k0 = tk * 32;
  const int tx = threadIdx.x & 31, ty = threadIdx.x >> 5;
#pragma unroll
  for (int r = 0; r < 4; ++r)
    tile[ty + r * 8][tx] = src[(size_t)(k0 + ty + r * 8) * N + n0 + tx];
  __syncthreads();
#pragma unroll
  for (int r = 0; r < 4; ++r)
    dst[(size_t)(n0 + ty + r * 8) * K + k0 + tx] = __float2bfloat16(tile[tx][ty + r * 8]);
}

// ---------------- GEMM: C = A[M,K] @ Bt[N,K]^T + bias ----------------
// 128x128 tile, BK=32, 4-deep LDS ring, counted vmcnt(8), T2 swizzle, T5 setprio,
// T1 bijective XCD swizzle (nwg % 8 == 0 for all our shapes).
// epi 0: fused QKV -> bf16 (Q scaled 0.125); epi 2: gelu -> bf16; epi 3: f32.
__global__ __launch_bounds__(256, 2) void gemm_bf16(
    const bf16* __restrict__ A, const bf16* __restrict__ Bt,
    void* __restrict__ out, const float* __restrict__ b0,
    const float* __restrict__ b1, const float* __restrict__ b2,
    int gx, int N, int K, int nt, int epi)
{
  __shared__ __align__(16) bf16 As[4][4096];   // 4 ring bufs x 128x32
  __shared__ __align__(16) bf16 Bs[4][4096];
  const int nwg = gridDim.x;
  const int wg = blockIdx.x;
  const int L = (wg & 7) * (nwg >> 3) + (wg >> 3);   // XCD-contiguous logical id
  const int bx = L % gx, by = L / gx;
  const int m0 = by * 128, n0 = bx * 128;

  const int t = threadIdx.x;
  const int lane = t & 63;
  const int w = t >> 6;
  const int wr = w >> 1, wc = w & 1;
  const int fr = lane & 15;
  const int g = lane >> 4;

  f32x4 acc[4][4];
#pragma unroll
  for (int i = 0; i < 4; ++i)
#pragma unroll
    for (int j = 0; j < 4; ++j) acc[i][j] = (f32x4)0.f;

  // staging: thread covers chunks {t, t+256} of each 512-chunk (16B) tile.
  // LDS dest linear; global source quarter pre-swizzled (rule 21).
  const int r0 = t >> 2, q0 = t & 3, r1 = r0 + 64;
  const int sq0 = q0 ^ ((r0 >> 1) & 3);
  const int sq1 = q0 ^ ((r1 >> 1) & 3);
  const bf16* gA0 = A + (size_t)(m0 + r0) * K + sq0 * 8;
  const bf16* gA1 = A + (size_t)(m0 + r1) * K + sq1 * 8;
  const bf16* gB0 = Bt + (size_t)(n0 + r0) * K + sq0 * 8;
  const bf16* gB1 = Bt + (size_t)(n0 + r1) * K + sq1 * 8;
  const int dst0 = t * 16, dst1 = t * 16 + 4096;   // byte offsets in buf

  // frag read byte offsets (swizzled to match)
  int offA[4], offB[4];
#pragma unroll
  for (int m = 0; m < 4; ++m) {
    const int rA = wr * 64 + m * 16 + fr;
    offA[m] = (rA * 64 + g * 16) ^ (((rA >> 1) & 3) << 4);
  }
#pragma unroll
  for (int n = 0; n < 4; ++n) {
    const int rB = wc * 64 + n * 16 + fr;
    offB[n] = (rB * 64 + g * 16) ^ (((rB >> 1) & 3) << 4);
  }

#define STAGE(KT, PB) { const int ko_ = (KT) << 5;                      \
    gload16(gA0 + ko_, (char*)As[PB] + dst0);                           \
    gload16(gA1 + ko_, (char*)As[PB] + dst1);                           \
    gload16(gB0 + ko_, (char*)Bs[PB] + dst0);                           \
    gload16(gB1 + ko_, (char*)Bs[PB] + dst1); }

  // prologue: stage tiles 0,1,2 ; wait tile0 (8 = tiles 1,2 outstanding)
  STAGE(0, 0) STAGE(1, 1) STAGE(2, 2)
  asm volatile("s_waitcnt vmcnt(8)" ::: "memory");
  __builtin_amdgcn_s_barrier();
  __builtin_amdgcn_sched_barrier(0);

#define GSTEP(KT, CB, PB) {                                             \
    const int pf_ = ((KT) + 3 < nt) ? (KT) + 3 : nt - 1;                \
    STAGE(pf_, PB)                                                      \
    bf16x8 af[4], bfr[4];                                               \
    _Pragma("unroll")                                                   \
    for (int m = 0; m < 4; ++m)                                         \
      af[m] = *(const bf16x8*)((const char*)As[CB] + offA[m]);          \
    _Pragma("unroll")                                                   \
    for (int n = 0; n < 4; ++n)                                         \
      bfr[n] = *(const bf16x8*)((const char*)Bs[CB] + offB[n]);         \
    __builtin_amdgcn_s_setprio(1);                                      \
    _Pragma("unroll")                                                   \
    for (int m = 0; m < 4; ++m)                                         \
      _Pragma("unroll")                                                 \
      for (int n = 0; n < 4; ++n)                                       \
        acc[m][n] = __builtin_amdgcn_mfma_f32_16x16x32_bf16(af[m], bfr[n], acc[m][n], 0, 0, 0); \
    __builtin_amdgcn_s_setprio(0);                                      \
    __builtin_amdgcn_sched_barrier(0);                                  \
    asm volatile("s_waitcnt vmcnt(8)" ::: "memory");                    \
    __builtin_amdgcn_s_barrier();                                       \
    __builtin_amdgcn_sched_barrier(0); }

#pragma unroll 1
  for (int kt = 0; kt < nt; kt += 4) {   // nt divisible by 4 for all shapes
    GSTEP(kt + 0, 0, 3)
    GSTEP(kt + 1, 1, 0)
    GSTEP(kt + 2, 2, 1)
    GSTEP(kt + 3, 3, 2)
  }
  asm volatile("s_waitcnt vmcnt(0)" ::: "memory");
#undef GSTEP
#undef STAGE

  const int rr = (lane >> 4) * 4;
  const int cc0 = lane & 15;
  if (epi == 0) {
    const int mat = n0 / HDIM;
    const float* bias = (mat == 0) ? b0 : (mat == 1) ? b1 : b2;
    const float qs = (mat == 0) ? 0.125f : 1.0f;
    bf16* dst = (bf16*)out + (size_t)mat * MROWS * HDIM;
    const int nl = n0 - mat * HDIM;
#pragma unroll
    for (int m = 0; m < 4; ++m)
#pragma unroll
      for (int n = 0; n < 4; ++n) {
        const int row = m0 + wr * 64 + m * 16 + rr;
        const int col = nl + wc * 64 + n * 16 + cc0;
        const float bv = bias[col];
#pragma unroll
        for (int r = 0; r < 4; ++r)
          dst[(size_t)(row + r) * HDIM + col] = __float2bfloat16((acc[m][n][r] + bv) * qs);
      }
  } else if (epi == 2) {
    bf16* dst = (bf16*)out;
#pragma unroll
    for (int m = 0; m < 4; ++m)
#pragma unroll
      for (int n = 0; n < 4; ++n) {
        const int row = m0 + wr * 64 + m * 16 + rr;
        const int col = n0 + wc * 64 + n * 16 + cc0;
        const float bv = b0[col];
#pragma unroll
        for (int r = 0; r < 4; ++r)
          dst[(size_t)(row + r) * N + col] = __float2bfloat16(gelu_f(acc[m][n][r] + bv));
      }
  } else {
    float* dst = (float*)out;
#pragma unroll
    for (int m = 0; m < 4; ++m)
#pragma unroll
      for (int n = 0; n < 4; ++n) {
        const int row = m0 + wr * 64 + m * 16 + rr;
        const int col = n0 + wc * 64 + n * 16 + cc0;
        const float bv = b0[col];
#pragma unroll
        for (int r = 0; r < 4; ++r)
          dst[(size_t)(row + r) * N + col] = acc[m][n][r] + bv;
      }
  }
}

// ---------------- MFMA sliding-window attention ----------------
__global__ __launch_bounds__(256) void attn_mfma(
    const bf16* __restrict__ qkv, bf16* __restrict__ attb)
{
  const int c = blockIdx.x, h = blockIdx.y, b = blockIdx.z;
  __shared__ unsigned int Vtw[64 * 64];
  __shared__ __align__(16) bf16 Pl[4][32 * 40];
  const int t = threadIdx.x;
  const int lane = t & 63;
  const int w = t >> 6;
  const int fr = lane & 15;
  const int g = lane >> 4;
  const bf16* Km = qkv + (size_t)4718592;
  const bf16* Vm = qkv + (size_t)9437184;
  const size_t qrow0 = (size_t)(b * 768 + c * 128);

  bf16x8 qf[2][2];
#pragma unroll
  for (int nt = 0; nt < 2; ++nt)
#pragma unroll
    for (int ks = 0; ks < 2; ++ks)
      qf[nt][ks] = *(const bf16x8*)(qkv + (qrow0 + w * 32 + nt * 16 + fr) * HDIM + h * 64 + ks * 32 + g * 8);

  f32x4 oacc[4][2];
#pragma unroll
  for (int i = 0; i < 4; ++i) { oacc[i][0] = (f32x4)0.f; oacc[i][1] = (f32x4)0.f; }
  float mrun[2] = {-1e30f, -1e30f};
  float lrun[2] = {0.f, 0.f};

#pragma unroll 1
  for (int cc = c - 1; cc <= c + 1; ++cc) {
    if (cc < 0 || cc >= NCHUNK) continue;
    __syncthreads();
    {
      const int d0 = (t & 7) * 8;
#pragma unroll
      for (int half = 0; half < 2; ++half) {
        const int kp2 = (t >> 3) + half * 32;
        const bf16* vr = Vm + ((size_t)(b * 768 + cc * 128) + kp2 * 2) * HDIM + h * 64 + d0;
        uint4 r0 = *(const uint4*)vr;
        uint4 r1 = *(const uint4*)(vr + HDIM);
        unsigned int a0[4] = {r0.x, r0.y, r0.z, r0.w};
        unsigned int a1[4] = {r1.x, r1.y, r1.z, r1.w};
#pragma unroll
        for (int e = 0; e < 8; ++e) {
          const int d = d0 + e;
          unsigned int lo = (a0[e >> 1] >> ((e & 1) * 16)) & 0xffffu;
          unsigned int hi = (a1[e >> 1] >> ((e & 1) * 16)) & 0xffffu;
          unsigned int byteoff = (unsigned int)(d * 256 + kp2 * 4);
          byteoff ^= ((((d >> 3) ^ d) & 7) << 4);
          Vtw[byteoff >> 2] = lo | (hi << 16);
        }
      }
    }
    __syncthreads();
    const int mode = (cc < c) ? 0 : (cc == c ? 1 : 2);
    const bf16* Kc = Km + ((size_t)(b * 768 + cc * 128)) * HDIM + h * 64;

#pragma unroll 1
    for (int kb = 0; kb < 4; ++kb) {
      f32x4 sacc[2][2];
      sacc[0][0] = sacc[0][1] = sacc[1][0] = sacc[1][1] = (f32x4)0.f;
#pragma unroll
      for (int ks = 0; ks < 2; ++ks)
#pragma unroll
        for (int mt = 0; mt < 2; ++mt) {
          bf16x8 kf = *(const bf16x8*)(Kc + (size_t)(kb * 32 + mt * 16 + fr) * HDIM + ks * 32 + g * 8);
          sacc[mt][0] = __builtin_amdgcn_mfma_f32_16x16x32_bf16(kf, qf[0][ks], sacc[mt][0], 0, 0, 0);
          sacc[mt][1] = __builtin_amdgcn_mfma_f32_16x16x32_bf16(kf, qf[1][ks], sacc[mt][1], 0, 0, 0);
        }
#pragma unroll
      for (int nt = 0; nt < 2; ++nt) {
        const int iq = w * 32 + nt * 16 + fr;
        float pm = -1e30f;
#pragma unroll
        for (int mt = 0; mt < 2; ++mt)
#pragma unroll
          for (int r = 0; r < 4; ++r) {
            const int j = kb * 32 + mt * 16 + g * 4 + r;
            const bool valid = (mode == 1) || (mode == 0 ? (j >= iq) : (j <= iq));
            const float sv = valid ? sacc[mt][nt][r] : -1e30f;
            sacc[mt][nt][r] = sv;
            pm = fmaxf(pm, sv);
          }
        pm = fmaxf(pm, __shfl_xor(pm, 16));
        pm = fmaxf(pm, __shfl_xor(pm, 32));
        const float mnew = fmaxf(fmaxf(mrun[nt], pm), -1e20f);
        const float sc = __expf(mrun[nt] - mnew);
        mrun[nt] = mnew;
        lrun[nt] *= sc;
#pragma unroll
        for (int mt = 0; mt < 4; ++mt) oacc[mt][nt] *= sc;
        float ps = 0.f;
#pragma unroll
        for (int mt = 0; mt < 2; ++mt) {
          union { bf16 hh[4]; uint2 uu; } pk;
#pragma unroll
          for (int r = 0; r < 4; ++r) {
            const float p = __expf(sacc[mt][nt][r] - mnew);
            ps += p;
            pk.hh[r] = __float2bfloat16(p);
          }
          *(uint2*)(&Pl[w][(nt * 16 + fr) * 40 + mt * 16 + g * 4]) = pk.uu;
        }
        ps += __shfl_xor(ps, 16);
        ps += __shfl_xor(ps, 32);
        lrun[nt] += ps;
      }
      bf16x8 bpf[2];
#pragma unroll
      for (int nt = 0; nt < 2; ++nt)
        bpf[nt] = *(const bf16x8*)(&Pl[w][(nt * 16 + fr) * 40 + g * 8]);
#pragma unroll
      for (int mt = 0; mt < 4; ++mt) {
        const int d = mt * 16 + fr;
        unsigned int byteoff = (unsigned int)(d * 256 + kb * 64 + g * 16);
        byteoff ^= ((((d >> 3) ^ d) & 7) << 4);
        bf16x8 vf = *(const bf16x8*)((const char*)Vtw + byteoff);
        oacc[mt][0] = __builtin_amdgcn_mfma_f32_16x16x32_bf16(vf, bpf[0], oacc[mt][0], 0, 0, 0);
        oacc[mt][1] = __builtin_amdgcn_mfma_f32_16x16x32_bf16(vf, bpf[1], oacc[mt][1], 0, 0, 0);
      }
    }
  }
#pragma unroll
  for (int nt = 0; nt < 2; ++nt) {
    const float rl = 1.f / lrun[nt];
    bf16* orow = attb + (qrow0 + w * 32 + nt * 16 + fr) * HDIM + h * 64;
#pragma unroll
    for (int mt = 0; mt < 4; ++mt) {
      union { bf16 hh[4]; uint2 uu; } ok;
#pragma unroll
      for (int r = 0; r < 4; ++r) ok.hh[r] = __float2bfloat16(oacc[mt][nt][r] * rl);
      *(uint2*)(orow + mt * 16 + g * 4) = ok.uu;
    }
  }
}

// ---------------- LayerNorm kernels ----------------
__device__ __forceinline__ void blk_reduce2(float& s1, float& s2) {
#pragma unroll
  for (int o = 32; o > 0; o >>= 1) { s1 += __shfl_xor(s1, o); s2 += __shfl_xor(s2, o); }
  __shared__ float red[8];
  const int w = threadIdx.x >> 6;
  if ((threadIdx.x & 63) == 0) { red[w] = s1; red[4 + w] = s2; }
  __syncthreads();
  s1 = red[0] + red[1] + red[2] + red[3];
  s2 = red[4] + red[5] + red[6] + red[7];
}

__global__ __launch_bounds__(256) void embed_ln(
    const float* __restrict__ emb, const float* __restrict__ pos,
    const float* __restrict__ tte, const float* __restrict__ g,
    const float* __restrict__ bt, float* __restrict__ x, bf16* __restrict__ xb)
{
  const int row = blockIdx.x;
  const int s = row % 768;
  const int t = threadIdx.x;
  const size_t base = (size_t)row * HDIM;
  const size_t pbase = (size_t)(s + 2) * HDIM;
  float v[3];
#pragma unroll
  for (int i = 0; i < 3; ++i) {
    const int idx = t + i * 256;
    v[i] = emb[base + idx] + pos[pbase + idx] + tte[idx];
  }
  float s1 = v[0] + v[1] + v[2];
  float s2 = v[0]*v[0] + v[1]*v[1] + v[2]*v[2];
  blk_reduce2(s1, s2);
  const float mu = s1 * (1.f / 768.f);
  const float var = s2 * (1.f / 768.f) - mu * mu;
  const float inv = rsqrtf(var + 1e-12f);
#pragma unroll
  for (int i = 0; i < 3; ++i) {
    const int idx = t + i * 256;
    const float o = (v[i] - mu) * inv * g[idx] + bt[idx];
    x[base + idx] = o;
    xb[base + idx] = __float2bfloat16(o);
  }
}

__global__ __launch_bounds__(256) void add_ln(
    const float* __restrict__ tmp, float* __restrict__ x, bf16* __restrict__ xb,
    const float* __restrict__ g, const float* __restrict__ bt)
{
  const int row = blockIdx.x;
  const int t = threadIdx.x;
  const size_t base = (size_t)row * HDIM;
  float v[3];
#pragma unroll
  for (int i = 0; i < 3; ++i) {
    const int idx = t + i * 256;
    v[i] = x[base + idx] + tmp[base + idx];
  }
  float s1 = v[0] + v[1] + v[2];
  float s2 = v[0]*v[0] + v[1]*v[1] + v[2]*v[2];
  blk_reduce2(s1, s2);
  const float mu = s1 * (1.f / 768.f);
  const float var = s2 * (1.f / 768.f) - mu * mu;
  const float inv = rsqrtf(var + 1e-12f);
#pragma unroll
  for (int i = 0; i < 3; ++i) {
    const int idx = t + i * 256;
    const float o = (v[i] - mu) * inv * g[idx] + bt[idx];
    x[base + idx] = o;
    xb[base + idx] = __float2bfloat16(o);
  }
}

// ---------------- gate ----------------
__global__ __launch_bounds__(256) void gate_kernel(
    const float* __restrict__ x, const float* __restrict__ gw,
    const float* __restrict__ gb, float* __restrict__ out)
{
  const int row = blockIdx.x * 4 + (threadIdx.x >> 6);
  const int lane = threadIdx.x & 63;
  const float* xr = x + (size_t)row * HDIM;
  float s = 0.f;
#pragma unroll
  for (int i = 0; i < 12; ++i) s += xr[lane + i * 64] * gw[lane + i * 64];
#pragma unroll
  for (int o = 32; o > 0; o >>= 1) s += __shfl_xor(s, o);
  if (lane == 0) out[row] = s + gb[0];
}

// ---------------- host ----------------
extern "C" void kernel_launch(void* const* d_in, const int* in_sizes, int n_in,
                              void* d_out, int out_size, void* d_ws, size_t ws_size,
                              hipStream_t stream)
{
  const float* emb = (const float*)d_in[0];
  const float* pos = (const float*)d_in[2];
  const float* tte = (const float*)d_in[3];
  const float* eg  = (const float*)d_in[4];
  const float* eb  = (const float*)d_in[5];
  const float* Wq  = (const float*)d_in[6];
  const float* bq  = (const float*)d_in[7];
  const float* Wk  = (const float*)d_in[8];
  const float* bk  = (const float*)d_in[9];
  const float* Wv  = (const float*)d_in[10];
  const float* bv  = (const float*)d_in[11];
  const float* Wo  = (const float*)d_in[12];
  const float* bo  = (const float*)d_in[13];
  const float* g1  = (const float*)d_in[14];
  const float* be1 = (const float*)d_in[15];
  const float* Wi  = (const float*)d_in[16];
  const float* bi  = (const float*)d_in[17];
  const float* Wo2 = (const float*)d_in[18];
  const float* bo2 = (const float*)d_in[19];
  const float* g2  = (const float*)d_in[20];
  const float* be2 = (const float*)d_in[21];
  const float* gw  = (const float*)d_in[22];
  const float* gb  = (const float*)d_in[23];

  char* wsp = (char*)d_ws;
  bf16* wt   = (bf16*)wsp;
  bf16* xb   = (bf16*)(wsp + 14155776);
  bf16* qkvb = (bf16*)(wsp + 23592960);
  float* tmp = (float*)(wsp + 61341696);
  bf16* attb = qkvb + (size_t)3 * 4718592;
  bf16* ffb  = qkvb;                 // alias: q/k/v/att dead when FFN1 runs
  float* x   = (float*)d_out;        // f32 residual stream lives in d_out
  float* gate = x + 4718592;

  embed_ln<<<6144, 256, 0, stream>>>(emb, pos, tte, eg, eb, x, xb);

  for (int l = 0; l < 12; ++l) {
    wconv<<<6912, 256, 0, stream>>>(Wq + (size_t)l * 589824, Wk + (size_t)l * 589824,
                                    Wv + (size_t)l * 589824, Wo + (size_t)l * 589824,
                                    Wi + (size_t)l * 2359296, Wo2 + (size_t)l * 2359296, wt);
    // QKV: M=6144 N=2304 K=768  -> grid 18*48=864
    gemm_bf16<<<864, 256, 0, stream>>>(xb, wt, qkvb,
        bq + l * 768, bk + l * 768, bv + l * 768, 18, 2304, 768, 24, 0);
    attn_mfma<<<dim3(6, 12, 8), 256, 0, stream>>>(qkvb, attb);
    // OProj: N=768 K=768 -> grid 6*48=288
    gemm_bf16<<<288, 256, 0, stream>>>(attb, wt + 1769472, tmp,
        bo + l * 768, nullptr, nullptr, 6, 768, 768, 24, 3);
    add_ln<<<6144, 256, 0, stream>>>(tmp, x, xb, g1 + l * 768, be1 + l * 768);
    // FFN1: N=3072 K=768 -> grid 24*48=1152
    gemm_bf16<<<1152, 256, 0, stream>>>(xb, wt + 2359296, ffb,
        bi + l * 3072, nullptr, nullptr, 24, 3072, 768, 24, 2);
    // FFN2: N=768 K=3072 -> grid 6*48=288
    gemm_bf16<<<288, 256, 0, stream>>>(ffb, wt + 4718592, tmp,
        bo2 + l * 768, nullptr, nullptr, 6, 768, 3072, 96, 3);
    add_ln<<<6144, 256, 0, stream>>>(tmp, x, xb, g2 + l * 768, be2 + l * 768);
  }

  gate_kernel<<<1536, 256, 0, stream>>>(x, gw, gb, gate);
}